// Round 5
// baseline (78.434 us; speedup 1.0000x reference)
//
#include <hip/hip_runtime.h>
#include <hip/hip_fp16.h>

// Problem constants (from reference setup_inputs)
#define BZ    32
#define NPTS  16384
#define NSMP  4096
#define KNB   64
#define NCH   6
#define RDISC 0.05f

#define WGS     256      // threads per wg == samples per wg (1 lane = 1 sample)
#define NBUCKET 16       // table split into 16 buckets of 1024 rows
#define LDS_PAD 12288    // pad LDS to 56KB -> at most 2 wg/CU (L1 window control)

// ---- pre-pass: pack feature table to fp16 rows padded to 16B -------------
// One aligned dwordx4 gather per row; one cache line per row; 16KB per bucket.
__global__ __launch_bounds__(256) void pnpp_pack(
    const float* __restrict__ feat, uint4* __restrict__ ptab)
{
    const int r = blockIdx.x * 256 + threadIdx.x;      // row 0..524287
    const float* src = feat + (size_t)r * NCH;
    const float4 a = *(const float4*)src;              // 8B-aligned dwordx4 (HW-ok)
    const float2 b = *(const float2*)(src + 4);
    uint4 v;
    v.x = (unsigned)__half_as_ushort(__float2half(a.x))
        | ((unsigned)__half_as_ushort(__float2half(a.y)) << 16);
    v.y = (unsigned)__half_as_ushort(__float2half(a.z))
        | ((unsigned)__half_as_ushort(__float2half(a.w)) << 16);
    v.z = (unsigned)__half_as_ushort(__float2half(b.x))
        | ((unsigned)__half_as_ushort(__float2half(b.y)) << 16);
    v.w = 0;
    ptab[r] = v;
}

// ---- main kernel ----------------------------------------------------------
// Per wg: 256 samples, 1 lane = 1 sample. Each lane bucket-sorts its 64
// (idx,ind) entries into LDS (counting sort, packed-u64 histograms), then for
// each of 16 buckets walks only its entries in that bucket, gathering rows
// from the packed global table. Bucket window = 16KB -> L1-resident; the
// per-bucket barrier keeps all waves of the wg inside the same window.
template<bool PACKED>
__global__ __launch_bounds__(256, 2) void pnpp_main(
    const float* __restrict__ feat,     // [BZ*NPTS*NCH] f32
    const uint4* __restrict__ ptab,     // [BZ*NPTS] packed fp16 rows
    const int*   __restrict__ nk_idx,   // [BZ*NSMP*KNB]
    const float* __restrict__ nk_dist,  // [BZ*NSMP*KNB]
    const int*   __restrict__ fps_idx,  // [BZ*NSMP]
    float*       __restrict__ out)      // [BZ*NSMP*11]
{
    __shared__ unsigned short ent[KNB * WGS + LDS_PAD];   // 56KB (32KB used)

    const int tid = threadIdx.x;
    const int bid = blockIdx.x;
    // XCD swizzle: contiguous work per XCD -> per-XCD L2 sees ~2 batch tables
    const int work = (bid & 7) * (gridDim.x >> 3) + (bid >> 3);
    const int wg0 = work * WGS;
    const int s   = wg0 + tid;          // this lane's sample
    const int b   = wg0 >> 12;          // batch (4096 samples per batch)

    // ---- phase 0: load 64 (idx,dist); pack entries; histogram by bucket
    unsigned er[32];                    // 64 u16 entries, 2 per dword
    unsigned long long c0 = 0, c1 = 0;  // 16 x 8-bit bucket counts
    {
        const int4*   ip = (const int4*)  (nk_idx  + (size_t)s * KNB);
        const float4* dp = (const float4*)(nk_dist + (size_t)s * KNB);
        #pragma unroll
        for (int c = 0; c < 16; ++c) {
            const int4   i4 = ip[c];
            const float4 d4 = dp[c];
            const unsigned e0 = (unsigned)i4.x | ((d4.x <= RDISC) ? 0x8000u : 0u);
            const unsigned e1 = (unsigned)i4.y | ((d4.y <= RDISC) ? 0x8000u : 0u);
            const unsigned e2 = (unsigned)i4.z | ((d4.z <= RDISC) ? 0x8000u : 0u);
            const unsigned e3 = (unsigned)i4.w | ((d4.w <= RDISC) ? 0x8000u : 0u);
            er[c * 2]     = e0 | (e1 << 16);
            er[c * 2 + 1] = e2 | (e3 << 16);
            #define HADD(ii) { const unsigned bk = ((unsigned)(ii)) >> 10;      \
                const unsigned long long inc = 1ull << ((bk & 7) * 8);          \
                if (bk < 8) c0 += inc; else c1 += inc; }
            HADD(i4.x) HADD(i4.y) HADD(i4.z) HADD(i4.w)
            #undef HADD
        }
    }

    // Exclusive prefix over the 16 bucket counts (packed bytes).
    unsigned long long p0 = 0, p1 = 0;
    {
        unsigned run = 0;
        #pragma unroll
        for (int k = 0; k < 8; ++k) {
            p0 |= (unsigned long long)run << (k * 8);
            run += (unsigned)((c0 >> (k * 8)) & 0xffULL);
        }
        #pragma unroll
        for (int k = 0; k < 8; ++k) {
            p1 |= (unsigned long long)run << (k * 8);
            run += (unsigned)((c1 >> (k * 8)) & 0xffULL);
        }
    }

    // ---- counting-scatter entries bucket-sorted into LDS [pos][sample]
    {
        unsigned long long b0 = p0, b1 = p1;
        #pragma unroll
        for (int k = 0; k < 64; ++k) {
            const unsigned e  = (k & 1) ? (er[k >> 1] >> 16) : (er[k >> 1] & 0xffffu);
            const unsigned bk = (e & 0x3fffu) >> 10;
            const unsigned sh = (bk & 7) * 8;
            const unsigned long long inc = 1ull << sh;
            unsigned pos;
            if (bk < 8) { pos = (unsigned)((b0 >> sh) & 0xffULL); b0 += inc; }
            else        { pos = (unsigned)((b1 >> sh) & 0xffULL); b1 += inc; }
            ent[pos * WGS + tid] = (unsigned short)e;
        }
    }

    // Sampled point features (f32, full precision; tiny gather volume)
    const int pidx = fps_idx[s];
    const float* fsrow = feat + (size_t)pidx * NCH;
    const float4 fa  = *(const float4*)(fsrow);
    const float2 fb2 = *(const float2*)(fsrow + 4);
    const float fs0 = fa.x, fs1 = fa.y, fs2 = fa.z;
    const float fs3 = fa.w, fs4 = fb2.x, fs5 = fb2.y;
    const float qs1 = fs0*fs0 + fs1*fs1 + fs2*fs2;
    const float qs2 = fs3*fs3 + fs4*fs4 + fs5*fs5;

    __syncthreads();   // ent visible to all waves

    // ---- accumulators (lane-private; no cross-lane reduction)
    float cntM = 0.f;
    float s0=0.f,s1=0.f,s2=0.f,s3=0.f,s4=0.f,s5=0.f;   // masked sums
    float m0=0.f,m1=0.f,m2=0.f;                        // unmasked xyz sums
    float cA=0.f,cB=0.f;                               // cosine sums

    const uint4* tb = ptab + (size_t)b * NPTS;
    const float* fbatch = feat + (size_t)b * (NPTS * NCH);

    #pragma unroll
    for (int p = 0; p < NBUCKET; ++p) {
        unsigned cur  = (unsigned)(((p < 8 ? p0 : p1) >> ((p & 7) * 8)) & 0xffULL);
        const int pn = p + 1;
        const unsigned endv = (p == 15) ? 64u
            : (unsigned)(((pn < 8 ? p0 : p1) >> ((pn & 7) * 8)) & 0xffULL);

        while (cur < endv) {
            const unsigned e = ent[cur * WGS + tid];
            ++cur;
            const unsigned idx = e & 0x3fffu;
            const float ind = (e & 0x8000u) ? 1.f : 0.f;
            float f0, f1, f2, f3, f4, f5;
            if (PACKED) {
                const uint4 v = tb[idx];   // 16B row, single line, L1-resident
                f0 = __half2float(__ushort_as_half((unsigned short)(v.x & 0xffffu)));
                f1 = __half2float(__ushort_as_half((unsigned short)(v.x >> 16)));
                f2 = __half2float(__ushort_as_half((unsigned short)(v.y & 0xffffu)));
                f3 = __half2float(__ushort_as_half((unsigned short)(v.y >> 16)));
                f4 = __half2float(__ushort_as_half((unsigned short)(v.z & 0xffffu)));
                f5 = __half2float(__ushort_as_half((unsigned short)(v.z >> 16)));
            } else {
                const float* fr = fbatch + (size_t)idx * NCH;
                const float4 A = *(const float4*)(fr);
                const float2 B = *(const float2*)(fr + 4);
                f0 = A.x; f1 = A.y; f2 = A.z; f3 = A.w; f4 = B.x; f5 = B.y;
            }

            cntM += ind;
            s0 += ind*f0; s1 += ind*f1; s2 += ind*f2;
            s3 += ind*f3; s4 += ind*f4; s5 += ind*f5;
            m0 += f0; m1 += f1; m2 += f2;

            const float q1 = f0*f0 + f1*f1 + f2*f2;
            const float n1 = fs0*f0 + fs1*f1 + fs2*f2;
            cA += n1 * __builtin_amdgcn_rsqf(qs1 * q1);
            const float q2 = f3*f3 + f4*f4 + f5*f5;
            const float n2 = fs3*f3 + fs4*f4 + fs5*f5;
            cB += n2 * __builtin_amdgcn_rsqf(qs2 * q2);
        }
        __syncthreads();   // keep all waves of the wg in the same L1 window
    }

    // ---- finalize
    const float rc = __builtin_amdgcn_rcpf(cntM);
    const float d0 = fs0 - s0*rc, d1 = fs1 - s1*rc, d2 = fs2 - s2*rc;
    const float d3 = fs3 - s3*rc, d4 = fs4 - s4*rc, d5 = fs5 - s5*rc;
    const float ik = 1.f / (float)KNB;
    const float o6 = cA * ik, o7 = cB * ik;
    const float ax = m0 * ik, ay = m1 * ik, az = m2 * ik;
    const float o8  = fs1*az - fs2*ay;
    const float o9  = fs2*ax - fs0*az;
    const float o10 = fs0*ay - fs1*ax;

    // ---- LDS-staged coalesced output (reuse ent; last barrier covers it)
    float* ostage = (float*)(void*)ent;   // 11264B of 56KB
    ostage[tid * 11 + 0]  = d0;
    ostage[tid * 11 + 1]  = d1;
    ostage[tid * 11 + 2]  = d2;
    ostage[tid * 11 + 3]  = d3;
    ostage[tid * 11 + 4]  = d4;
    ostage[tid * 11 + 5]  = d5;
    ostage[tid * 11 + 6]  = o6;
    ostage[tid * 11 + 7]  = o7;
    ostage[tid * 11 + 8]  = o8;
    ostage[tid * 11 + 9]  = o9;
    ostage[tid * 11 + 10] = o10;
    __syncthreads();
    const size_t obase = (size_t)wg0 * 11;
    #pragma unroll
    for (int i = 0; i < 11; ++i)
        out[obase + i * WGS + tid] = ostage[i * WGS + tid];
}

extern "C" void kernel_launch(void* const* d_in, const int* in_sizes, int n_in,
                              void* d_out, int out_size, void* d_ws, size_t ws_size,
                              hipStream_t stream) {
    const float* feat = (const float*)d_in[0];
    const int*   nki  = (const int*)  d_in[1];
    const float* nkd  = (const float*)d_in[2];
    const int*   fps  = (const int*)  d_in[3];
    float* out = (float*)d_out;

    const size_t need = (size_t)BZ * NPTS * sizeof(uint4);   // 8 MB
    const int blocks = (BZ * NSMP) / WGS;                    // 512

    if (ws_size >= need) {
        uint4* ptab = (uint4*)d_ws;
        pnpp_pack<<<dim3((BZ * NPTS) / 256), dim3(256), 0, stream>>>(feat, ptab);
        pnpp_main<true><<<dim3(blocks), dim3(WGS), 0, stream>>>(
            feat, ptab, nki, nkd, fps, out);
    } else {
        pnpp_main<false><<<dim3(blocks), dim3(WGS), 0, stream>>>(
            feat, (const uint4*)nullptr, nki, nkd, fps, out);
    }
}

// Round 6
// 71.573 us; speedup vs baseline: 1.0959x; 1.0959x over previous
//
#include <hip/hip_runtime.h>
#include <hip/hip_fp16.h>

// Problem constants (from reference setup_inputs)
#define BZ    32
#define NPTS  16384
#define NSMP  4096
#define KNB   64
#define NCH   6
#define RDISC 0.05f

#define WGS   512       // threads per wg == samples per wg (1 lane = 1 sample)
#define NPASS 8         // table chunks (buckets) of CROWS rows
#define CROWS 2048      // rows per chunk (NPTS / NPASS)

__device__ __forceinline__ unsigned pkh(float x, float y) {
    return (unsigned)__half_as_ushort(__float2half(x))
         | ((unsigned)__half_as_ushort(__float2half(y)) << 16);
}

// ---- pre-pass: pack feature table to fp16 rows padded to 16B --------------
__global__ __launch_bounds__(256) void pnpp_pack(
    const float* __restrict__ feat, uint4* __restrict__ ptab)
{
    const int r = blockIdx.x * 256 + threadIdx.x;      // row 0..524287
    const float* src = feat + (size_t)r * NCH;
    const float4 a = *(const float4*)src;              // 8B-aligned dwordx4
    const float2 b = *(const float2*)(src + 4);
    ptab[r] = make_uint4(pkh(a.x, a.y), pkh(a.z, a.w), pkh(b.x, b.y), 0u);
}

// ---- main kernel ----------------------------------------------------------
// wg = 512 samples, 1 lane = 1 sample, 1 wg/CU (LDS 96KB). Each lane
// bucket-sorts its 64 (idx,ind) entries into LDS by table-chunk; the table is
// then walked chunk-by-chunk: chunk staged in LDS as fp16 16B rows
// (ds_read_b128, conflict-light), next chunk's global loads issued BEFORE the
// walk (T14 async-stage split). Walk has wave-uniform trip count (wave-max)
// so the compiler can pipeline across iterations. XCD swizzle: all 8 wgs of
// a batch land on one XCD -> batch table is L2-resident after first touch.
template<bool PACKED>
__global__ __launch_bounds__(512, 2) void pnpp_main(
    const float* __restrict__ feat,     // [BZ*NPTS*NCH] f32
    const uint4* __restrict__ ptab,     // [BZ*NPTS] packed fp16 rows
    const int*   __restrict__ nk_idx,   // [BZ*NSMP*KNB]
    const float* __restrict__ nk_dist,  // [BZ*NSMP*KNB]
    const int*   __restrict__ fps_idx,  // [BZ*NSMP]
    float*       __restrict__ out)      // [BZ*NSMP*11]
{
    __shared__ unsigned short ent[KNB * WGS];   // 64KB sorted entries [pos][sample]
    __shared__ uint4 chunkbuf[CROWS];           // 32KB fp16 rows of current chunk

    const int tid = threadIdx.x;
    const int bid = blockIdx.x;
    // XCD swizzle: XCD k runs works [32k, 32k+32) = batches [4k, 4k+4)
    const int w   = (bid & 7) * (gridDim.x >> 3) + (bid >> 3);
    const int wg0 = w * WGS;
    const int s   = wg0 + tid;          // this lane's sample
    const int b   = s >> 12;            // batch (4096 samples per batch)

    // ---- phase 0: load 64 (idx,dist); pack entries; 8-bucket histogram
    unsigned er[32];                    // 64 u16 entries, 2 per dword
    unsigned long long cnt = 0;         // 8 x 8-bit bucket counts
    {
        const int4*   ip = (const int4*)  (nk_idx  + (size_t)s * KNB);
        const float4* dp = (const float4*)(nk_dist + (size_t)s * KNB);
        #pragma unroll
        for (int c = 0; c < 16; ++c) {
            const int4   i4 = ip[c];
            const float4 d4 = dp[c];
            const unsigned e0 = (unsigned)i4.x | ((d4.x <= RDISC) ? 0x8000u : 0u);
            const unsigned e1 = (unsigned)i4.y | ((d4.y <= RDISC) ? 0x8000u : 0u);
            const unsigned e2 = (unsigned)i4.z | ((d4.z <= RDISC) ? 0x8000u : 0u);
            const unsigned e3 = (unsigned)i4.w | ((d4.w <= RDISC) ? 0x8000u : 0u);
            er[c * 2]     = e0 | (e1 << 16);
            er[c * 2 + 1] = e2 | (e3 << 16);
            cnt += 1ull << (((unsigned)i4.x >> 11) * 8);
            cnt += 1ull << (((unsigned)i4.y >> 11) * 8);
            cnt += 1ull << (((unsigned)i4.z >> 11) * 8);
            cnt += 1ull << (((unsigned)i4.w >> 11) * 8);
        }
    }

    // Exclusive prefix over the 8 packed bucket counts.
    unsigned long long cum = 0;
    {
        unsigned run = 0;
        #pragma unroll
        for (int k = 0; k < 8; ++k) {
            cum |= (unsigned long long)run << (k * 8);
            run += (unsigned)((cnt >> (k * 8)) & 0xffULL);
        }
    }

    // ---- counting-scatter entries bucket-sorted into LDS [pos][sample]
    {
        unsigned long long base = cum;
        #pragma unroll
        for (int k = 0; k < 64; ++k) {
            const unsigned e  = (k & 1) ? (er[k >> 1] >> 16) : (er[k >> 1] & 0xffffu);
            const unsigned bk = (e & 0x3fffu) >> 11;
            const unsigned pos = (unsigned)((base >> (bk * 8)) & 0xffULL);
            ent[pos * WGS + tid] = (unsigned short)e;
            base += 1ull << (bk * 8);
        }
    }

    // Sampled point features (f32, tiny gather volume)
    const int pidx = fps_idx[s];
    const float* fsrow = feat + (size_t)pidx * NCH;
    const float4 fa  = *(const float4*)(fsrow);
    const float2 fb2 = *(const float2*)(fsrow + 4);
    const float fs0 = fa.x, fs1 = fa.y, fs2 = fa.z;
    const float fs3 = fa.w, fs4 = fb2.x, fs5 = fb2.y;
    const float qs1 = fs0*fs0 + fs1*fs1 + fs2*fs2;
    const float qs2 = fs3*fs3 + fs4*fs4 + fs5*fs5;

    const uint4* tb      = ptab + (size_t)b * NPTS;
    const float* fbatch  = feat + (size_t)b * (NPTS * NCH);

    // ---- stage chunk 0
    #define SLOAD(P, ST)                                                        \
        if (PACKED) {                                                           \
            _Pragma("unroll")                                                   \
            for (int i = 0; i < 4; ++i) ST[i] = tb[(P) * CROWS + i * WGS + tid];\
        } else {                                                                \
            _Pragma("unroll")                                                   \
            for (int i = 0; i < 4; ++i) {                                       \
                const int r = (P) * CROWS + i * WGS + tid;                      \
                const float* fr = fbatch + (size_t)r * NCH;                     \
                const float2 A = *(const float2*)(fr);                          \
                const float2 Bv = *(const float2*)(fr + 2);                     \
                const float2 Cv = *(const float2*)(fr + 4);                     \
                ST[i] = make_uint4(pkh(A.x, A.y), pkh(Bv.x, Bv.y),              \
                                   pkh(Cv.x, Cv.y), 0u);                        \
            }                                                                   \
        }
    #define SWRITE(ST)                                                          \
        { _Pragma("unroll")                                                     \
          for (int i = 0; i < 4; ++i) chunkbuf[i * WGS + tid] = ST[i]; }

    {
        uint4 st[4];
        SLOAD(0, st);
        SWRITE(st);
    }
    __syncthreads();   // ent + chunk0 visible

    // ---- accumulators (lane-private; no cross-lane reduction)
    float cntM = 0.f;
    float s0=0.f,s1=0.f,s2=0.f,s3=0.f,s4=0.f,s5=0.f;   // masked sums
    float m0=0.f,m1=0.f,m2=0.f;                        // unmasked xyz sums
    float cA=0.f,cB=0.f;                               // cosine sums

    #pragma unroll
    for (int p = 0; p < NPASS; ++p) {
        uint4 st[4];
        if (p < NPASS - 1) { SLOAD(p + 1, st); }       // issue early (T14)

        unsigned cur  = (unsigned)((cum >> (p * 8)) & 0xffULL);
        const unsigned endv = (p < NPASS - 1)
            ? (unsigned)((cum >> (p * 8 + 8)) & 0xffULL) : 64u;
        int n = (int)(endv - cur);
        #pragma unroll
        for (int m = 1; m < 64; m <<= 1) {             // wave-max trip count
            const int o = __shfl_xor(n, m, 64);
            n = (o > n) ? o : n;
        }

        #pragma unroll 2
        for (int k = 0; k < n; ++k) {
            const bool act = (cur + (unsigned)k) < endv;
            const unsigned pos = act ? (cur + (unsigned)k) : 63u;
            const unsigned e = ent[pos * WGS + tid];
            if (act) {
                const unsigned ridx = e & 0x3fffu;
                const uint4 v = chunkbuf[ridx & (CROWS - 1)];
                const float f0 = __half2float(__ushort_as_half((unsigned short)(v.x & 0xffffu)));
                const float f1 = __half2float(__ushort_as_half((unsigned short)(v.x >> 16)));
                const float f2 = __half2float(__ushort_as_half((unsigned short)(v.y & 0xffffu)));
                const float f3 = __half2float(__ushort_as_half((unsigned short)(v.y >> 16)));
                const float f4 = __half2float(__ushort_as_half((unsigned short)(v.z & 0xffffu)));
                const float f5 = __half2float(__ushort_as_half((unsigned short)(v.z >> 16)));
                const float ind = (e & 0x8000u) ? 1.f : 0.f;

                cntM += ind;
                s0 += ind*f0; s1 += ind*f1; s2 += ind*f2;
                s3 += ind*f3; s4 += ind*f4; s5 += ind*f5;
                m0 += f0; m1 += f1; m2 += f2;

                const float q1 = f0*f0 + f1*f1 + f2*f2;
                const float n1 = fs0*f0 + fs1*f1 + fs2*f2;
                cA += n1 * __builtin_amdgcn_rsqf(qs1 * q1);
                const float q2 = f3*f3 + f4*f4 + f5*f5;
                const float n2 = fs3*f3 + fs4*f4 + fs5*f5;
                cB += n2 * __builtin_amdgcn_rsqf(qs2 * q2);
            }
        }
        __syncthreads();                       // all done reading chunkbuf
        if (p < NPASS - 1) {
            SWRITE(st);                        // write next chunk
            __syncthreads();                   // visible before next walk
        }
    }

    // ---- finalize
    const float rc = __builtin_amdgcn_rcpf(cntM);
    const float d0 = fs0 - s0*rc, d1 = fs1 - s1*rc, d2 = fs2 - s2*rc;
    const float d3 = fs3 - s3*rc, d4 = fs4 - s4*rc, d5 = fs5 - s5*rc;
    const float ik = 1.f / (float)KNB;
    const float o6 = cA * ik, o7 = cB * ik;
    const float ax = m0 * ik, ay = m1 * ik, az = m2 * ik;
    const float o8  = fs1*az - fs2*ay;
    const float o9  = fs2*ax - fs0*az;
    const float o10 = fs0*ay - fs1*ax;

    // ---- LDS-staged coalesced output (reuse chunkbuf; loop barrier covers it)
    float* ostage = (float*)(void*)chunkbuf;   // 22528B of 32KB
    ostage[tid * 11 + 0]  = d0;
    ostage[tid * 11 + 1]  = d1;
    ostage[tid * 11 + 2]  = d2;
    ostage[tid * 11 + 3]  = d3;
    ostage[tid * 11 + 4]  = d4;
    ostage[tid * 11 + 5]  = d5;
    ostage[tid * 11 + 6]  = o6;
    ostage[tid * 11 + 7]  = o7;
    ostage[tid * 11 + 8]  = o8;
    ostage[tid * 11 + 9]  = o9;
    ostage[tid * 11 + 10] = o10;
    __syncthreads();
    const size_t obase = (size_t)wg0 * 11;
    #pragma unroll
    for (int i = 0; i < 11; ++i)
        out[obase + i * WGS + tid] = ostage[i * WGS + tid];
}

extern "C" void kernel_launch(void* const* d_in, const int* in_sizes, int n_in,
                              void* d_out, int out_size, void* d_ws, size_t ws_size,
                              hipStream_t stream) {
    const float* feat = (const float*)d_in[0];
    const int*   nki  = (const int*)  d_in[1];
    const float* nkd  = (const float*)d_in[2];
    const int*   fps  = (const int*)  d_in[3];
    float* out = (float*)d_out;

    const size_t need = (size_t)BZ * NPTS * sizeof(uint4);   // 8 MB
    const int blocks = (BZ * NSMP) / WGS;                    // 256

    if (ws_size >= need) {
        uint4* ptab = (uint4*)d_ws;
        pnpp_pack<<<dim3((BZ * NPTS) / 256), dim3(256), 0, stream>>>(feat, ptab);
        pnpp_main<true><<<dim3(blocks), dim3(WGS), 0, stream>>>(
            feat, ptab, nki, nkd, fps, out);
    } else {
        pnpp_main<false><<<dim3(blocks), dim3(WGS), 0, stream>>>(
            feat, (const uint4*)nullptr, nki, nkd, fps, out);
    }
}